// Round 1
// baseline (239.827 us; speedup 1.0000x reference)
//
#include <hip/hip_runtime.h>

// LSTM: B=8192 sequences, T=512 steps, D=5 input, H=10 hidden, Linear(10,1) head.
// Layout: 16 lanes per sequence; lane j<10 owns hidden unit j (computes its
// i,f,g,o gate rows + cell/hidden update). h broadcast within the 16-lane
// group via __shfl (no LDS, no barriers). 512 blocks x 256 thr = 2048 waves
// = exactly 2 waves/SIMD on MI355X, perfectly balanced.

#define BATCH  8192
#define SEQLEN 512
#define INSZ   5
#define HID    10

__device__ __forceinline__ float fast_sigmoid(float x) {
    // 1/(1+2^(-x*log2e)); v_exp_f32 + v_rcp_f32, ~1ulp each
    float e = __builtin_amdgcn_exp2f(-1.442695040888963f * x);
    return __builtin_amdgcn_rcpf(1.0f + e);
}

__device__ __forceinline__ float fast_tanh(float x) {
    // 1 - 2/(1+2^(x*2*log2e)); handles +/-inf saturation correctly
    float e = __builtin_amdgcn_exp2f(2.885390081777927f * x);
    float r = __builtin_amdgcn_rcpf(1.0f + e);
    return fmaf(-2.0f, r, 1.0f);
}

__global__ __launch_bounds__(256, 2) void lstm_fused(
    const float* __restrict__ x,     // [B, T, D]
    const float* __restrict__ Wih,   // [4H, D]
    const float* __restrict__ Whh,   // [4H, H]
    const float* __restrict__ bih,   // [4H]
    const float* __restrict__ bhh,   // [4H]
    const float* __restrict__ Wout,  // [1, H]
    const float* __restrict__ bout,  // [1]
    float* __restrict__ out)         // [B, 1]
{
    const int tid = blockIdx.x * blockDim.x + threadIdx.x;
    const int seq = tid >> 4;         // 0..8191
    const int j   = tid & 15;         // lane within group
    const int ju  = (j < HID) ? j : 0; // lanes 10..15 duplicate unit 0 (never read)

    // Per-lane weights: gate rows {ju, H+ju, 2H+ju, 3H+ju} (i,f,g,o order)
    float wih[4][INSZ], whh[4][HID], bias[4];
#pragma unroll
    for (int g = 0; g < 4; ++g) {
        const int row = g * HID + ju;
#pragma unroll
        for (int k = 0; k < INSZ; ++k) wih[g][k] = Wih[row * INSZ + k];
#pragma unroll
        for (int k = 0; k < HID; ++k)  whh[g][k] = Whh[row * HID + k];
        bias[g] = bih[row] + bhh[row];
    }

    const float* xp = x + (size_t)seq * SEQLEN * INSZ;
    float h = 0.0f, c = 0.0f;

    for (int t = 0; t < SEQLEN; ++t) {
        // x_t (all 16 lanes of the group load the same 5 floats; L1 broadcast)
        float xv[INSZ];
#pragma unroll
        for (int k = 0; k < INSZ; ++k) xv[k] = xp[t * INSZ + k];

        // broadcast h vector across the 16-lane group
        float hv[HID];
#pragma unroll
        for (int k = 0; k < HID; ++k) hv[k] = __shfl(h, k, 16);

        float a0 = bias[0], a1 = bias[1], a2 = bias[2], a3 = bias[3];
#pragma unroll
        for (int k = 0; k < INSZ; ++k) {
            a0 = fmaf(wih[0][k], xv[k], a0);
            a1 = fmaf(wih[1][k], xv[k], a1);
            a2 = fmaf(wih[2][k], xv[k], a2);
            a3 = fmaf(wih[3][k], xv[k], a3);
        }
#pragma unroll
        for (int k = 0; k < HID; ++k) {
            a0 = fmaf(whh[0][k], hv[k], a0);
            a1 = fmaf(whh[1][k], hv[k], a1);
            a2 = fmaf(whh[2][k], hv[k], a2);
            a3 = fmaf(whh[3][k], hv[k], a3);
        }

        const float ig = fast_sigmoid(a0);
        const float fg = fast_sigmoid(a1);
        const float gg = fast_tanh(a2);
        const float og = fast_sigmoid(a3);
        c = fmaf(fg, c, ig * gg);
        h = og * fast_tanh(c);
    }

    // head: out[seq] = sum_j Wout[j]*h_j + bout
    float p = (j < HID) ? Wout[ju] * h : 0.0f;
    p += __shfl_xor(p, 8, 16);
    p += __shfl_xor(p, 4, 16);
    p += __shfl_xor(p, 2, 16);
    p += __shfl_xor(p, 1, 16);
    if (j == 0) out[seq] = p + bout[0];
}

extern "C" void kernel_launch(void* const* d_in, const int* in_sizes, int n_in,
                              void* d_out, int out_size, void* d_ws, size_t ws_size,
                              hipStream_t stream) {
    const float* x    = (const float*)d_in[0];
    const float* Wih  = (const float*)d_in[1];
    const float* Whh  = (const float*)d_in[2];
    const float* bih  = (const float*)d_in[3];
    const float* bhh  = (const float*)d_in[4];
    const float* Wout = (const float*)d_in[5];
    const float* bout = (const float*)d_in[6];
    float* out = (float*)d_out;

    const int threads = 256;
    const int blocks  = (BATCH * 16) / threads;  // 512
    lstm_fused<<<blocks, threads, 0, stream>>>(x, Wih, Whh, bih, bhh, Wout, bout, out);
}

// Round 2
// 178.328 us; speedup vs baseline: 1.3449x; 1.3449x over previous
//
#include <hip/hip_runtime.h>

// LSTM: B=8192 seqs, T=512, D=5, H=10, Linear(10,1) head.
// 16 lanes/seq (lane j<10 owns hidden unit j), 2048 waves = 2/SIMD.
// R2: software-pipelined step — h-broadcast shuffles issue first, then the
// recurrence-independent next-step x-load + x*Wih accumulation fills the
// bpermute/VMEM latency window, then the hW FMAs and batched activations.

#define BATCH  8192
#define SEQLEN 512
#define INSZ   5
#define HID    10

#define L2E  1.442695040888963f   // log2(e)
#define L2E2 2.885390081777927f   // 2*log2(e)

__device__ __forceinline__ float fast_sigmoid(float x) {
    float e = __builtin_amdgcn_exp2f(-L2E * x);
    return __builtin_amdgcn_rcpf(1.0f + e);
}

__global__ __launch_bounds__(256, 2) void lstm_fused(
    const float* __restrict__ x,     // [B, T, D]
    const float* __restrict__ Wih,   // [4H, D]
    const float* __restrict__ Whh,   // [4H, H]
    const float* __restrict__ bih,   // [4H]
    const float* __restrict__ bhh,   // [4H]
    const float* __restrict__ Wout,  // [1, H]
    const float* __restrict__ bout,  // [1]
    float* __restrict__ out)         // [B, 1]
{
    const int tid = blockIdx.x * blockDim.x + threadIdx.x;
    const int seq = tid >> 4;
    const int j   = tid & 15;
    const int ju  = (j < HID) ? j : 0;   // pad lanes duplicate unit 0 (never read)

    float wih[4][INSZ], whh[4][HID], bias[4];
#pragma unroll
    for (int g = 0; g < 4; ++g) {
        const int row = g * HID + ju;
#pragma unroll
        for (int k = 0; k < INSZ; ++k) wih[g][k] = Wih[row * INSZ + k];
#pragma unroll
        for (int k = 0; k < HID; ++k)  whh[g][k] = Whh[row * HID + k];
        bias[g] = bih[row] + bhh[row];
    }

    const float* xp = x + (size_t)seq * SEQLEN * INSZ;
    float h = 0.0f, c = 0.0f;

    // prologue: x(0) -> xa(0)  (bias folded in)
    float xa0 = bias[0], xa1 = bias[1], xa2 = bias[2], xa3 = bias[3];
#pragma unroll
    for (int k = 0; k < INSZ; ++k) {
        const float xv = xp[k];
        xa0 = fmaf(wih[0][k], xv, xa0);
        xa1 = fmaf(wih[1][k], xv, xa1);
        xa2 = fmaf(wih[2][k], xv, xa2);
        xa3 = fmaf(wih[3][k], xv, xa3);
    }

#pragma unroll 2
    for (int t = 0; t < SEQLEN; ++t) {
        // (1) issue the h broadcast first (DS pipe, latency to hide)
        float hv[HID];
#pragma unroll
        for (int k = 0; k < HID; ++k) hv[k] = __shfl(h, k, 16);

        // (2) recurrence-independent: prefetch x(t+1), accumulate next xa.
        //     Clamped index (uniform cndmask, no branch) avoids OOB on last step.
        const int tn = (t + 1 < SEQLEN) ? (t + 1) : t;
        float nx0 = bias[0], nx1 = bias[1], nx2 = bias[2], nx3 = bias[3];
#pragma unroll
        for (int k = 0; k < INSZ; ++k) {
            const float xv = xp[tn * INSZ + k];
            nx0 = fmaf(wih[0][k], xv, nx0);
            nx1 = fmaf(wih[1][k], xv, nx1);
            nx2 = fmaf(wih[2][k], xv, nx2);
            nx3 = fmaf(wih[3][k], xv, nx3);
        }

        // (3) gates = xa + Whh * h
        float a0 = xa0, a1 = xa1, a2 = xa2, a3 = xa3;
#pragma unroll
        for (int k = 0; k < HID; ++k) {
            a0 = fmaf(whh[0][k], hv[k], a0);
            a1 = fmaf(whh[1][k], hv[k], a1);
            a2 = fmaf(whh[2][k], hv[k], a2);
            a3 = fmaf(whh[3][k], hv[k], a3);
        }

        // (4) batched activations: 4 independent exp2 first (trans pipe pipelines)
        const float e0 = __builtin_amdgcn_exp2f(-L2E * a0);
        const float e1 = __builtin_amdgcn_exp2f(-L2E * a1);
        const float eg = __builtin_amdgcn_exp2f( L2E2 * a2);
        const float e3 = __builtin_amdgcn_exp2f(-L2E * a3);
        const float ig = __builtin_amdgcn_rcpf(1.0f + e0);
        const float fg = __builtin_amdgcn_rcpf(1.0f + e1);
        const float rg = __builtin_amdgcn_rcpf(1.0f + eg);
        const float og = __builtin_amdgcn_rcpf(1.0f + e3);
        const float gg = fmaf(-2.0f, rg, 1.0f);        // tanh(a2)
        c = fmaf(fg, c, ig * gg);
        const float ec = __builtin_amdgcn_exp2f(L2E2 * c);
        const float rc = __builtin_amdgcn_rcpf(1.0f + ec);
        h = og * fmaf(-2.0f, rc, 1.0f);                // og * tanh(c)

        xa0 = nx0; xa1 = nx1; xa2 = nx2; xa3 = nx3;
    }

    // head: out[seq] = sum_j Wout[j]*h_j + bout
    float p = (j < HID) ? Wout[ju] * h : 0.0f;
    p += __shfl_xor(p, 8, 16);
    p += __shfl_xor(p, 4, 16);
    p += __shfl_xor(p, 2, 16);
    p += __shfl_xor(p, 1, 16);
    if (j == 0) out[seq] = p + bout[0];
}

extern "C" void kernel_launch(void* const* d_in, const int* in_sizes, int n_in,
                              void* d_out, int out_size, void* d_ws, size_t ws_size,
                              hipStream_t stream) {
    const float* x    = (const float*)d_in[0];
    const float* Wih  = (const float*)d_in[1];
    const float* Whh  = (const float*)d_in[2];
    const float* bih  = (const float*)d_in[3];
    const float* bhh  = (const float*)d_in[4];
    const float* Wout = (const float*)d_in[5];
    const float* bout = (const float*)d_in[6];
    float* out = (float*)d_out;

    const int threads = 256;
    const int blocks  = (BATCH * 16) / threads;  // 512
    lstm_fused<<<blocks, threads, 0, stream>>>(x, Wih, Whh, bih, bhh, Wout, bout, out);
}

// Round 3
// 168.368 us; speedup vs baseline: 1.4244x; 1.0592x over previous
//
#include <hip/hip_runtime.h>

// LSTM: B=8192 seqs, T=512, D=5, H=10, Linear(10,1) head.
// 16 lanes/seq (lane j<10 owns hidden unit j), 2048 waves = 2/SIMD.
// R3: packed-f32 math — gate pairs (i,f) and (g,o) computed with
// v_pk_fma_f32 (__builtin_elementwise_fma on float2), halving the 60
// FMA/step to 30 pk-FMA. x loaded as 5x dwordx4 per 4-step block with
// double-buffering (1.25 loads/step, latency fully hidden).

#define BATCH  8192
#define SEQLEN 512
#define INSZ   5
#define HID    10

#define L2E  1.442695040888963f   // log2(e)
#define L2E2 2.885390081777927f   // 2*log2(e)

typedef float f32x2 __attribute__((ext_vector_type(2)));
typedef float f32x4 __attribute__((ext_vector_type(4)));

__device__ __forceinline__ f32x2 pk_fma(f32x2 a, f32x2 b, f32x2 c) {
    return __builtin_elementwise_fma(a, b, c);
}

__global__ __launch_bounds__(256, 2) void lstm_fused(
    const float* __restrict__ x,     // [B, T, D]
    const float* __restrict__ Wih,   // [4H, D]
    const float* __restrict__ Whh,   // [4H, H]
    const float* __restrict__ bih,   // [4H]
    const float* __restrict__ bhh,   // [4H]
    const float* __restrict__ Wout,  // [1, H]
    const float* __restrict__ bout,  // [1]
    float* __restrict__ out)         // [B, 1]
{
    const int tid = blockIdx.x * blockDim.x + threadIdx.x;
    const int seq = tid >> 4;
    const int j   = tid & 15;
    const int ju  = (j < HID) ? j : 0;   // pad lanes duplicate unit 0 (never read)

    // Paired weights: lane j holds gate rows {ju, H+ju, 2H+ju, 3H+ju};
    // pack (i,f) -> .x/.y of *01, (g,o) -> .x/.y of *23.
    const int r0 = 0 * HID + ju, r1 = 1 * HID + ju;
    const int r2 = 2 * HID + ju, r3 = 3 * HID + ju;

    f32x2 wih01[INSZ], wih23[INSZ], whh01[HID], whh23[HID];
#pragma unroll
    for (int k = 0; k < INSZ; ++k) {
        wih01[k] = f32x2{ Wih[r0 * INSZ + k], Wih[r1 * INSZ + k] };
        wih23[k] = f32x2{ Wih[r2 * INSZ + k], Wih[r3 * INSZ + k] };
    }
#pragma unroll
    for (int k = 0; k < HID; ++k) {
        whh01[k] = f32x2{ Whh[r0 * HID + k], Whh[r1 * HID + k] };
        whh23[k] = f32x2{ Whh[r2 * HID + k], Whh[r3 * HID + k] };
    }
    const f32x2 b01 = f32x2{ bih[r0] + bhh[r0], bih[r1] + bhh[r1] };
    const f32x2 b23 = f32x2{ bih[r2] + bhh[r2], bih[r3] + bhh[r3] };

    const float* xp = x + (size_t)seq * SEQLEN * INSZ;

    // x double buffer: 4 steps = 20 floats = 5 aligned dwordx4 per block.
    float cx[20], nx[20];
    {
        const f32x4* v4 = reinterpret_cast<const f32x4*>(xp);
#pragma unroll
        for (int i = 0; i < 5; ++i) {
            f32x4 t = v4[i];
            cx[4 * i + 0] = t.x; cx[4 * i + 1] = t.y;
            cx[4 * i + 2] = t.z; cx[4 * i + 3] = t.w;
        }
    }

    float h = 0.0f, c = 0.0f;

#pragma unroll 2
    for (int tb = 0; tb < SEQLEN; tb += 4) {
        // prefetch next block's x (clamped on last block; harmless reload)
        const int nb = (tb + 4 < SEQLEN) ? (tb + 4) : tb;
        const f32x4* v4 = reinterpret_cast<const f32x4*>(xp + nb * INSZ);
#pragma unroll
        for (int i = 0; i < 5; ++i) {
            f32x4 t = v4[i];
            nx[4 * i + 0] = t.x; nx[4 * i + 1] = t.y;
            nx[4 * i + 2] = t.z; nx[4 * i + 3] = t.w;
        }

#pragma unroll
        for (int s = 0; s < 4; ++s) {
            // (1) h broadcast first (DS pipe latency to hide)
            float hv[HID];
#pragma unroll
            for (int k = 0; k < HID; ++k) hv[k] = __shfl(h, k, 16);

            // (2) x part for this sub-step (registers, overlaps bpermute wait)
            f32x2 a01 = b01, a23 = b23;
#pragma unroll
            for (int k = 0; k < INSZ; ++k) {
                const float xk = cx[s * INSZ + k];
                const f32x2 xv = f32x2{ xk, xk };
                a01 = pk_fma(wih01[k], xv, a01);
                a23 = pk_fma(wih23[k], xv, a23);
            }

            // (3) recurrent part
#pragma unroll
            for (int k = 0; k < HID; ++k) {
                const f32x2 hk = f32x2{ hv[k], hv[k] };
                a01 = pk_fma(whh01[k], hk, a01);
                a23 = pk_fma(whh23[k], hk, a23);
            }

            // (4) activations: 4 independent exp2 first, then rcps
            const float e0 = __builtin_amdgcn_exp2f(-L2E  * a01.x);
            const float e1 = __builtin_amdgcn_exp2f(-L2E  * a01.y);
            const float eg = __builtin_amdgcn_exp2f( L2E2 * a23.x);
            const float e3 = __builtin_amdgcn_exp2f(-L2E  * a23.y);
            const float ig = __builtin_amdgcn_rcpf(1.0f + e0);
            const float fg = __builtin_amdgcn_rcpf(1.0f + e1);
            const float rg = __builtin_amdgcn_rcpf(1.0f + eg);
            const float og = __builtin_amdgcn_rcpf(1.0f + e3);
            const float gg = fmaf(-2.0f, rg, 1.0f);        // tanh(g)
            c = fmaf(fg, c, ig * gg);
            const float ec = __builtin_amdgcn_exp2f(L2E2 * c);
            const float rc = __builtin_amdgcn_rcpf(1.0f + ec);
            h = og * fmaf(-2.0f, rc, 1.0f);                // o * tanh(c)
        }

#pragma unroll
        for (int i = 0; i < 20; ++i) cx[i] = nx[i];
    }

    // head: out[seq] = sum_j Wout[j]*h_j + bout
    float p = (j < HID) ? Wout[ju] * h : 0.0f;
    p += __shfl_xor(p, 8, 16);
    p += __shfl_xor(p, 4, 16);
    p += __shfl_xor(p, 2, 16);
    p += __shfl_xor(p, 1, 16);
    if (j == 0) out[seq] = p + bout[0];
}

extern "C" void kernel_launch(void* const* d_in, const int* in_sizes, int n_in,
                              void* d_out, int out_size, void* d_ws, size_t ws_size,
                              hipStream_t stream) {
    const float* x    = (const float*)d_in[0];
    const float* Wih  = (const float*)d_in[1];
    const float* Whh  = (const float*)d_in[2];
    const float* bih  = (const float*)d_in[3];
    const float* bhh  = (const float*)d_in[4];
    const float* Wout = (const float*)d_in[5];
    const float* bout = (const float*)d_in[6];
    float* out = (float*)d_out;

    const int threads = 256;
    const int blocks  = (BATCH * 16) / threads;  // 512
    lstm_fused<<<blocks, threads, 0, stream>>>(x, Wih, Whh, bih, bhh, Wout, bout, out);
}